// Round 6
// baseline (98.002 us; speedup 1.0000x reference)
//
#include <hip/hip_runtime.h>

namespace {
constexpr int kH = 192, kW = 640, kHW = kH * kW;
constexpr int kW4g = kW / 4;            // 160 granules per row
constexpr int kHW4 = kHW / 4;           // 30720 granules per plane
constexpr int kB = 2, kC = 64;          // batch, image channels
constexpr int kN0 = 40000, kC0 = 32;    // level0 points/channels
constexpr int kN1 = 20000, kC1 = 64;    // level1 points/channels
constexpr int kCL = 67;                 // C1 + 3
constexpr int kBHW = kB * kHW;
// zero-padded y planes: 18 = 9 taps x B, rows H+2, pitch W+8 (interior at +1,+4)
constexpr int kPH = kH + 2, kPW = kW + 8;  // 194 x 648
constexpr int kPlane = kPH * kPW;          // 125712
constexpr int kYPF = 18 * kPlane;          // 2,262,816 floats (9.05 MB)
constexpr int kYP4 = kYPF / 4;             // 565,704
constexpr int kWin4 = 2 * kBHW / 4;        // 122,880

// ---------------------------------------------------------------------------
// init: zero the padded y buffer (borders must be 0 each replay) and fill the
// two winner maps with -1. One launch, float4/int4 stores.
// ---------------------------------------------------------------------------
__global__ __launch_bounds__(256) void kinit(float4* __restrict__ yp4,
                                             int4* __restrict__ win4) {
  int i = blockIdx.x * 256 + threadIdx.x;
  if (i < kYP4) {
    yp4[i] = make_float4(0.f, 0.f, 0.f, 0.f);
  } else {
    int j = i - kYP4;
    if (j < kWin4) win4[j] = make_int4(-1, -1, -1, -1);
  }
}

// ---------------------------------------------------------------------------
// blocks 0..468: winner-index scatter (last-write-wins == max index wins)
// block 469: fold all linear stages into per-tap matrices:
//   b' = W2@b0+b2; A1 = Wsp^T@W2 [9,67]; M0 = A1@W0 [9,35];
//   sb_k = Wsp[:,k].b'; wsum_k = sum_c Wsp[c,k]
// ---------------------------------------------------------------------------
__global__ __launch_bounds__(256) void kscatter_precomp(
    const float* __restrict__ coor0, const float* __restrict__ coor1,
    int* __restrict__ win0, int* __restrict__ win1,
    const float* __restrict__ W0, const float* __restrict__ b0,
    const float* __restrict__ W2, const float* __restrict__ b2,
    const float* __restrict__ Wsp, float* __restrict__ M0,
    float* __restrict__ A1g, float* __restrict__ sb,
    float* __restrict__ wsum) {
  if (blockIdx.x < 469) {  // ---- scatter ----
    int idx = blockIdx.x * 256 + threadIdx.x;
    const float* coor;
    int* win;
    int N;
    if (idx < kB * kN0) {
      coor = coor0; win = win0; N = kN0;
    } else {
      idx -= kB * kN0;
      if (idx >= kB * kN1) return;
      coor = coor1; win = win1; N = kN1;
    }
    int b = idx / N;
    float u = coor[(size_t)idx * 2 + 0];
    float v = coor[(size_t)idx * 2 + 1];
    u = fminf(fmaxf(u, 0.f), 1.f);
    v = fminf(fmaxf(v, 0.f), 1.f);
    int r = (int)(v * (float)kH);  // row from coor[:,1]
    int c = (int)(u * (float)kW);  // col from coor[:,0]
    if (r < kH && c < kW) {
      int n = idx - b * N;
      atomicMax(&win[b * kHW + r * kW + c], n);
    }
    return;
  }
  // ---- precomp (single block) ----
  __shared__ float A1s[9 * kCL];
  __shared__ float bps[kCL];
  const int t = threadIdx.x;
  if (t < kCL) {
    float s = b2[t];
    for (int j = 0; j < kCL; ++j) s += W2[t * kCL + j] * b0[j];
    bps[t] = s;
  }
  for (int idx = t; idx < 9 * kCL; idx += 256) {
    int k = idx / kCL, j = idx - k * kCL;
    float s = 0.f;
    for (int c = 0; c < kCL; ++c) s += Wsp[c * 9 + k] * W2[c * kCL + j];
    A1s[idx] = s;
    A1g[idx] = s;
  }
  __syncthreads();
  for (int idx = t; idx < 9 * 35; idx += 256) {
    int k = idx / 35, i = idx - k * 35;
    float s = 0.f;
    for (int j = 0; j < kCL; ++j) s += A1s[k * kCL + j] * W0[j * 35 + i];
    M0[idx] = s;
  }
  if (t < 9) {
    float s = 0.f;
    for (int c = 0; c < kCL; ++c) s += Wsp[c * 9 + t] * bps[c];
    sb[t] = s;
  } else if (t >= 16 && t < 25) {
    int k = t - 16;
    float s = 0.f;
    for (int c = 0; c < kCL; ++c) s += Wsp[c * 9 + k];
    wsum[k] = s;
  }
}

// ---------------------------------------------------------------------------
// pass1 (fused gate + tap projection), 1 pixel/thread, 960 blocks.
// phase1: gate partial sums over 16-ch chunks with float4 x loads -> LDS
// phase2: g from LDS; per-pixel feature gathers; y[9] -> padded planes
//   y[k][pix] = wsum[k]*g + sb[k] + [w0>=0] M0[k].p0 + [w1>=0] A1[k].p1
// ---------------------------------------------------------------------------
__global__ __launch_bounds__(256) void kpass1(
    const float* __restrict__ x_rgb, const int* __restrict__ win0,
    const int* __restrict__ win1, const float* __restrict__ feat0,
    const float* __restrict__ vox0, const float* __restrict__ feat1,
    const float* __restrict__ vox1, const float* __restrict__ M0,
    const float* __restrict__ A1, const float* __restrict__ sb,
    const float* __restrict__ wsum, const float* __restrict__ W3,
    const float* __restrict__ b3, float* __restrict__ yp) {
  __shared__ float part[64][4][4];  // [granule][chunk][elem]
  const int tid = threadIdx.x;
  const int P0 = blockIdx.x * 256;     // first pixel of block
  const int b = P0 / kHW;              // uniform per block (480 blocks/batch)
  // ---- phase1: gate partials ----
  {
    const int g = tid >> 2, q = tid & 3;
    const int pg = (P0 - b * kHW) / 4 + g;  // plane-local granule
    const float4* xr = (const float4*)(x_rgb + (size_t)b * kC * kHW) + pg;
    float4 acc = make_float4(0.f, 0.f, 0.f, 0.f);
#pragma unroll
    for (int cc = 0; cc < 16; ++cc) {
      const int c = q * 16 + cc;
      float wv = W3[c];
      float4 x4 = xr[(size_t)c * kHW4];
      acc.x += wv * x4.x;
      acc.y += wv * x4.y;
      acc.z += wv * x4.z;
      acc.w += wv * x4.w;
    }
    part[g][q][0] = acc.x;
    part[g][q][1] = acc.y;
    part[g][q][2] = acc.z;
    part[g][q][3] = acc.w;
  }
  __syncthreads();
  // ---- phase2: per-pixel ----
  const int pix = P0 + tid;
  const int pp = pix - b * kHW;
  const int h = pp / kW;
  const int w = pp - h * kW;
  const int g = tid >> 2, e = tid & 3;
  const float gv = b3[0] + part[g][0][e] + part[g][1][e] + part[g][2][e] +
                   part[g][3][e];
  float y[9];
#pragma unroll
  for (int k = 0; k < 9; ++k) y[k] = wsum[k] * gv + sb[k];

  const int w0 = win0[pix];
  if (w0 >= 0) {
    const float4* f0 = (const float4*)(feat0 + ((size_t)b * kN0 + w0) * kC0);
#pragma unroll
    for (int i4 = 0; i4 < 8; ++i4) {
      float4 v = f0[i4];
#pragma unroll
      for (int k = 0; k < 9; ++k) {
        const float* m = M0 + k * 35 + i4 * 4;
        y[k] += m[0] * v.x + m[1] * v.y + m[2] * v.z + m[3] * v.w;
      }
    }
    const float* v0 = vox0 + ((size_t)b * kN0 + w0) * 3;
#pragma unroll
    for (int i = 0; i < 3; ++i) {
      float v = v0[i];
#pragma unroll
      for (int k = 0; k < 9; ++k) y[k] += M0[k * 35 + kC0 + i] * v;
    }
  }
  const int w1 = win1[pix];
  if (w1 >= 0) {
    const float4* f1 = (const float4*)(feat1 + ((size_t)b * kN1 + w1) * kC1);
#pragma unroll
    for (int i4 = 0; i4 < 16; ++i4) {
      float4 v = f1[i4];
#pragma unroll
      for (int k = 0; k < 9; ++k) {
        const float* m = A1 + k * kCL + i4 * 4;
        y[k] += m[0] * v.x + m[1] * v.y + m[2] * v.z + m[3] * v.w;
      }
    }
    const float* v1 = vox1 + ((size_t)b * kN1 + w1) * 3;
#pragma unroll
    for (int i = 0; i < 3; ++i) {
      float v = v1[i];
#pragma unroll
      for (int k = 0; k < 9; ++k) y[k] += A1[k * kCL + kC1 + i] * v;
    }
  }
  // store into padded planes (coalesced dword stores per k)
#pragma unroll
  for (int k = 0; k < 9; ++k) {
    yp[((size_t)(k * kB + b) * kPH + (h + 1)) * kPW + 4 + w] = y[k];
  }
}

// ---------------------------------------------------------------------------
// pass2 (fused stencil+sigmoid+multiply): 4 px x 16 ch per thread, 960 blocks.
//   logit[p] = bsp + sum_k yp[k][p + off_k]  (padding zeros == skipped taps)
//   out[c,p] = x_rgb[c,p] * sigmoid(logit[p])
// ---------------------------------------------------------------------------
__global__ __launch_bounds__(256) void kpass2(const float* __restrict__ x_rgb,
                                              const float* __restrict__ yp,
                                              const float* __restrict__ bsp,
                                              float* __restrict__ out) {
  const int j = blockIdx.x * 256 + threadIdx.x;
  const int T = kB * kHW4;             // 61440 granules
  const int q = j / T;                 // channel chunk 0..3 (uniform/block)
  const int gran = j - q * T;
  const int b = gran / kHW4;
  const int p4 = gran - b * kHW4;
  const int h = p4 / kW4g;
  const int w4 = p4 - h * kW4g;

  const float bias = bsp[0];
  float4 lg = make_float4(bias, bias, bias, bias);
#pragma unroll
  for (int r = 0; r < 3; ++r) {
    const size_t rowoff = ((size_t)h + r) * kPW + 4 * w4;
    const float* pA = yp + (size_t)((3 * r + 0) * kB + b) * kPlane + rowoff;
    const float* pB = yp + (size_t)((3 * r + 1) * kB + b) * kPlane + rowoff;
    const float* pC = yp + (size_t)((3 * r + 2) * kB + b) * kPlane + rowoff;
    float LA = pA[3];
    float4 a4 = *(const float4*)(pA + 4);
    float4 b4 = *(const float4*)(pB + 4);
    float4 c4 = *(const float4*)(pC + 4);
    float RC = pC[8];
    lg.x += LA + b4.x + c4.y;
    lg.y += a4.x + b4.y + c4.z;
    lg.z += a4.y + b4.z + c4.w;
    lg.w += a4.z + b4.w + RC;
  }
  float4 att;
  att.x = 1.f / (1.f + __expf(-lg.x));
  att.y = 1.f / (1.f + __expf(-lg.y));
  att.z = 1.f / (1.f + __expf(-lg.z));
  att.w = 1.f / (1.f + __expf(-lg.w));

  const float4* xr = (const float4*)(x_rgb + (size_t)b * kC * kHW) + p4;
  float4* op = (float4*)(out + (size_t)b * kC * kHW) + p4;
#pragma unroll
  for (int cc = 0; cc < 16; ++cc) {
    const int c = q * 16 + cc;
    float4 x4 = xr[(size_t)c * kHW4];
    x4.x *= att.x;
    x4.y *= att.y;
    x4.z *= att.z;
    x4.w *= att.w;
    op[(size_t)c * kHW4] = x4;
  }
}

}  // namespace

extern "C" void kernel_launch(void* const* d_in, const int* in_sizes, int n_in,
                              void* d_out, int out_size, void* d_ws,
                              size_t ws_size, hipStream_t stream) {
  const float* x_rgb = (const float*)d_in[0];
  const float* feat0 = (const float*)d_in[1];
  const float* coor0 = (const float*)d_in[2];
  const float* vox0 = (const float*)d_in[3];
  const float* feat1 = (const float*)d_in[4];
  const float* coor1 = (const float*)d_in[5];
  const float* vox1 = (const float*)d_in[6];
  const float* W0 = (const float*)d_in[7];
  const float* b0 = (const float*)d_in[8];
  const float* W2 = (const float*)d_in[9];
  const float* b2 = (const float*)d_in[10];
  const float* W3 = (const float*)d_in[11];
  const float* b3 = (const float*)d_in[12];
  const float* Wsp = (const float*)d_in[13];
  const float* bsp = (const float*)d_in[14];
  float* out = (float*)d_out;

  // workspace: yp[18*194*648] | win0[BHW] | win1[BHW] | M0 | A1 | sb | wsum
  float* yp = (float*)d_ws;
  int* win0 = (int*)(yp + (size_t)kYPF);
  int* win1 = win0 + (size_t)kBHW;
  float* M0 = (float*)(win1 + (size_t)kBHW);
  float* A1 = M0 + 9 * 35;
  float* sb = A1 + 9 * kCL;
  float* wsum = sb + 9;

  const int ninit = kYP4 + kWin4;
  kinit<<<(ninit + 255) / 256, 256, 0, stream>>>((float4*)yp, (int4*)win0);
  kscatter_precomp<<<470, 256, 0, stream>>>(coor0, coor1, win0, win1, W0, b0,
                                            W2, b2, Wsp, M0, A1, sb, wsum);
  kpass1<<<kBHW / 256, 256, 0, stream>>>(x_rgb, win0, win1, feat0, vox0, feat1,
                                         vox1, M0, A1, sb, wsum, W3, b3, yp);
  kpass2<<<kB * kHW4 * 4 / 256, 256, 0, stream>>>(x_rgb, yp, bsp, out);
}

// Round 7
// 85.353 us; speedup vs baseline: 1.1482x; 1.1482x over previous
//
#include <hip/hip_runtime.h>

namespace {
constexpr int kH = 192, kW = 640, kHW = kH * kW;
constexpr int kW4g = kW / 4;            // 160 granules per row
constexpr int kHW4 = kHW / 4;           // 30720 granules per plane
constexpr int kB = 2, kC = 64;          // batch, image channels
constexpr int kN0 = 40000, kC0 = 32;    // level0 points/channels
constexpr int kN1 = 20000, kC1 = 64;    // level1 points/channels
constexpr int kCL = 67;                 // C1 + 3
constexpr int kBHW = kB * kHW;
// zero-padded y planes: 18 = 9 taps x B, rows H+2, pitch W+8 (interior at +1,+4)
constexpr int kPH = kH + 2, kPW = kW + 8;  // 194 x 648
constexpr int kPlane = kPH * kPW;          // 125712
constexpr int kYPF = 18 * kPlane;          // 2,262,816 floats (9.05 MB)
constexpr int kYP4 = kYPF / 4;
constexpr int kWin4 = 2 * kBHW / 4;

// ---------------------------------------------------------------------------
// init: zero padded y buffer (borders must be 0 each replay; interior is
// rewritten by kgy) and fill the two winner maps with -1.
// ---------------------------------------------------------------------------
__global__ __launch_bounds__(256) void kinit(float4* __restrict__ yp4,
                                             int4* __restrict__ win4) {
  int i = blockIdx.x * 256 + threadIdx.x;
  if (i < kYP4) {
    yp4[i] = make_float4(0.f, 0.f, 0.f, 0.f);
  } else {
    int j = i - kYP4;
    if (j < kWin4) win4[j] = make_int4(-1, -1, -1, -1);
  }
}

// ---------------------------------------------------------------------------
// blocks 0..468: winner-index scatter (last-write-wins == max index wins)
// block 469: LDS-staged fold of all linear stages:
//   b' = W2@b0+b2; A1 = Wsp^T@W2 [9,67]; M0 = A1@W0 [9,35];
//   sb_k = Wsp[:,k].b'; wsum_k = sum_c Wsp[c,k]
// All inner 67-chains read LDS (global loads are one coalesced staging pass).
// ---------------------------------------------------------------------------
__global__ __launch_bounds__(256) void kscatter_precomp(
    const float* __restrict__ coor0, const float* __restrict__ coor1,
    int* __restrict__ win0, int* __restrict__ win1,
    const float* __restrict__ W0, const float* __restrict__ b0,
    const float* __restrict__ W2, const float* __restrict__ b2,
    const float* __restrict__ Wsp, float* __restrict__ M0,
    float* __restrict__ A1g, float* __restrict__ sb,
    float* __restrict__ wsum) {
  __shared__ float W2s[kCL * kCL];   // 17.9 KB
  __shared__ float W0s[kCL * 35];    // 9.4 KB
  __shared__ float Wsps[kCL * 9];    // 2.4 KB
  __shared__ float A1s[9 * kCL];
  __shared__ float bps[kCL];
  if (blockIdx.x < 469) {  // ---- scatter ----
    int idx = blockIdx.x * 256 + threadIdx.x;
    const float* coor;
    int* win;
    int N;
    if (idx < kB * kN0) {
      coor = coor0; win = win0; N = kN0;
    } else {
      idx -= kB * kN0;
      if (idx >= kB * kN1) return;
      coor = coor1; win = win1; N = kN1;
    }
    int b = idx / N;
    float u = coor[(size_t)idx * 2 + 0];
    float v = coor[(size_t)idx * 2 + 1];
    u = fminf(fmaxf(u, 0.f), 1.f);
    v = fminf(fmaxf(v, 0.f), 1.f);
    int r = (int)(v * (float)kH);  // row from coor[:,1]
    int c = (int)(u * (float)kW);  // col from coor[:,0]
    if (r < kH && c < kW) {
      int n = idx - b * N;
      atomicMax(&win[b * kHW + r * kW + c], n);
    }
    return;
  }
  // ---- precomp (single block, LDS-staged) ----
  const int t = threadIdx.x;
  for (int i = t; i < kCL * kCL; i += 256) W2s[i] = W2[i];
  for (int i = t; i < kCL * 35; i += 256) W0s[i] = W0[i];
  for (int i = t; i < kCL * 9; i += 256) Wsps[i] = Wsp[i];
  __syncthreads();
  if (t < kCL) {
    float s = b2[t];
    for (int j = 0; j < kCL; ++j) s += W2s[t * kCL + j] * b0[j];
    bps[t] = s;
  }
  for (int idx = t; idx < 9 * kCL; idx += 256) {
    int k = idx / kCL, j = idx - k * kCL;
    float s = 0.f;
    for (int c = 0; c < kCL; ++c) s += Wsps[c * 9 + k] * W2s[c * kCL + j];
    A1s[idx] = s;
    A1g[idx] = s;
  }
  __syncthreads();
  for (int idx = t; idx < 9 * 35; idx += 256) {
    int k = idx / 35, i = idx - k * 35;
    float s = 0.f;
    for (int j = 0; j < kCL; ++j) s += A1s[k * kCL + j] * W0s[j * 35 + i];
    M0[idx] = s;
  }
  if (t < 9) {
    float s = 0.f;
    for (int c = 0; c < kCL; ++c) s += Wsps[c * 9 + t] * bps[c];
    sb[t] = s;
  } else if (t >= 16 && t < 25) {
    int k = t - 16;
    float s = 0.f;
    for (int c = 0; c < kCL; ++c) s += Wsps[c * 9 + k];
    wsum[k] = s;
  }
}

// ---------------------------------------------------------------------------
// gate partials: 4 channel-chunks x (B*HW/4) granules, 960 blocks.
// Each thread: one float4 granule over 16 channels (perfectly coalesced,
// q uniform per block -> W3 reads are scalar loads).
//   gpart[q][pix] = sum_{c in chunk q} W3[c] * x_rgb[b,c,pix]
// ---------------------------------------------------------------------------
__global__ __launch_bounds__(256) void kgate(const float* __restrict__ x_rgb,
                                             const float* __restrict__ W3,
                                             float* __restrict__ gpart) {
  const int j = blockIdx.x * 256 + threadIdx.x;
  const int T = kB * kHW4;             // 61440 granules
  const int q = j / T;                 // channel chunk 0..3 (uniform/block)
  const int gran = j - q * T;
  const int b = gran / kHW4;
  const int p4 = gran - b * kHW4;
  const float4* xr = (const float4*)(x_rgb + (size_t)b * kC * kHW) + p4;
  float4 acc = make_float4(0.f, 0.f, 0.f, 0.f);
#pragma unroll
  for (int cc = 0; cc < 16; ++cc) {
    const int c = q * 16 + cc;
    float wv = W3[c];
    float4 x4 = xr[(size_t)c * kHW4];
    acc.x += wv * x4.x;
    acc.y += wv * x4.y;
    acc.z += wv * x4.z;
    acc.w += wv * x4.w;
  }
  ((float4*)gpart)[j] = acc;
}

// ---------------------------------------------------------------------------
// per-SOURCE-pixel tap projection (gathers happen once, not 9x):
//   g = b3 + sum_q gpart[q][pix]
//   y[k][pix] = wsum[k]*g + sb[k] + [w0>=0] M0[k].p0 + [w1>=0] A1[k].p1
// written into zero-padded planes for the branch-free stencil pass.
// ---------------------------------------------------------------------------
__global__ __launch_bounds__(256) void kgy(
    const float* __restrict__ gpart, const int* __restrict__ win0,
    const int* __restrict__ win1, const float* __restrict__ feat0,
    const float* __restrict__ vox0, const float* __restrict__ feat1,
    const float* __restrict__ vox1, const float* __restrict__ M0,
    const float* __restrict__ A1, const float* __restrict__ sb,
    const float* __restrict__ wsum, const float* __restrict__ b3,
    float* __restrict__ yp) {
  const int pix = blockIdx.x * 256 + threadIdx.x;
  const int b = pix / kHW;
  const int pp = pix - b * kHW;
  const int h = pp / kW;
  const int w = pp - h * kW;
  const float gv = b3[0] + gpart[pix] + gpart[kBHW + pix] +
                   gpart[2 * kBHW + pix] + gpart[3 * kBHW + pix];
  float y[9];
#pragma unroll
  for (int k = 0; k < 9; ++k) y[k] = wsum[k] * gv + sb[k];

  const int w0 = win0[pix];
  if (w0 >= 0) {
    const float4* f0 = (const float4*)(feat0 + ((size_t)b * kN0 + w0) * kC0);
#pragma unroll
    for (int i4 = 0; i4 < 8; ++i4) {
      float4 v = f0[i4];
#pragma unroll
      for (int k = 0; k < 9; ++k) {
        const float* m = M0 + k * 35 + i4 * 4;
        y[k] += m[0] * v.x + m[1] * v.y + m[2] * v.z + m[3] * v.w;
      }
    }
    const float* v0 = vox0 + ((size_t)b * kN0 + w0) * 3;
#pragma unroll
    for (int i = 0; i < 3; ++i) {
      float v = v0[i];
#pragma unroll
      for (int k = 0; k < 9; ++k) y[k] += M0[k * 35 + kC0 + i] * v;
    }
  }
  const int w1 = win1[pix];
  if (w1 >= 0) {
    const float4* f1 = (const float4*)(feat1 + ((size_t)b * kN1 + w1) * kC1);
#pragma unroll
    for (int i4 = 0; i4 < 16; ++i4) {
      float4 v = f1[i4];
#pragma unroll
      for (int k = 0; k < 9; ++k) {
        const float* m = A1 + k * kCL + i4 * 4;
        y[k] += m[0] * v.x + m[1] * v.y + m[2] * v.z + m[3] * v.w;
      }
    }
    const float* v1 = vox1 + ((size_t)b * kN1 + w1) * 3;
#pragma unroll
    for (int i = 0; i < 3; ++i) {
      float v = v1[i];
#pragma unroll
      for (int k = 0; k < 9; ++k) y[k] += A1[k * kCL + kC1 + i] * v;
    }
  }
#pragma unroll
  for (int k = 0; k < 9; ++k) {
    yp[((size_t)(k * kB + b) * kPH + (h + 1)) * kPW + 4 + w] = y[k];
  }
}

// ---------------------------------------------------------------------------
// fused stencil+sigmoid+multiply: 4 px x 16 ch per thread, 960 blocks.
//   logit[p] = bsp + sum_k yp[k][p + off_k]  (padding zeros == skipped taps)
//   out[c,p] = x_rgb[c,p] * sigmoid(logit[p])
// ---------------------------------------------------------------------------
__global__ __launch_bounds__(256) void kpass2(const float* __restrict__ x_rgb,
                                              const float* __restrict__ yp,
                                              const float* __restrict__ bsp,
                                              float* __restrict__ out) {
  const int j = blockIdx.x * 256 + threadIdx.x;
  const int T = kB * kHW4;             // 61440 granules
  const int q = j / T;                 // channel chunk 0..3 (uniform/block)
  const int gran = j - q * T;
  const int b = gran / kHW4;
  const int p4 = gran - b * kHW4;
  const int h = p4 / kW4g;
  const int w4 = p4 - h * kW4g;

  const float bias = bsp[0];
  float4 lg = make_float4(bias, bias, bias, bias);
#pragma unroll
  for (int r = 0; r < 3; ++r) {
    const size_t rowoff = ((size_t)h + r) * kPW + 4 * w4;
    const float* pA = yp + (size_t)((3 * r + 0) * kB + b) * kPlane + rowoff;
    const float* pB = yp + (size_t)((3 * r + 1) * kB + b) * kPlane + rowoff;
    const float* pC = yp + (size_t)((3 * r + 2) * kB + b) * kPlane + rowoff;
    float LA = pA[3];
    float4 a4 = *(const float4*)(pA + 4);
    float4 b4 = *(const float4*)(pB + 4);
    float4 c4 = *(const float4*)(pC + 4);
    float RC = pC[8];
    lg.x += LA + b4.x + c4.y;
    lg.y += a4.x + b4.y + c4.z;
    lg.z += a4.y + b4.z + c4.w;
    lg.w += a4.z + b4.w + RC;
  }
  float4 att;
  att.x = 1.f / (1.f + __expf(-lg.x));
  att.y = 1.f / (1.f + __expf(-lg.y));
  att.z = 1.f / (1.f + __expf(-lg.z));
  att.w = 1.f / (1.f + __expf(-lg.w));

  const float4* xr = (const float4*)(x_rgb + (size_t)b * kC * kHW) + p4;
  float4* op = (float4*)(out + (size_t)b * kC * kHW) + p4;
#pragma unroll
  for (int cc = 0; cc < 16; ++cc) {
    const int c = q * 16 + cc;
    float4 x4 = xr[(size_t)c * kHW4];
    x4.x *= att.x;
    x4.y *= att.y;
    x4.z *= att.z;
    x4.w *= att.w;
    op[(size_t)c * kHW4] = x4;
  }
}

}  // namespace

extern "C" void kernel_launch(void* const* d_in, const int* in_sizes, int n_in,
                              void* d_out, int out_size, void* d_ws,
                              size_t ws_size, hipStream_t stream) {
  const float* x_rgb = (const float*)d_in[0];
  const float* feat0 = (const float*)d_in[1];
  const float* coor0 = (const float*)d_in[2];
  const float* vox0 = (const float*)d_in[3];
  const float* feat1 = (const float*)d_in[4];
  const float* coor1 = (const float*)d_in[5];
  const float* vox1 = (const float*)d_in[6];
  const float* W0 = (const float*)d_in[7];
  const float* b0 = (const float*)d_in[8];
  const float* W2 = (const float*)d_in[9];
  const float* b2 = (const float*)d_in[10];
  const float* W3 = (const float*)d_in[11];
  const float* b3 = (const float*)d_in[12];
  const float* Wsp = (const float*)d_in[13];
  const float* bsp = (const float*)d_in[14];
  float* out = (float*)d_out;

  // workspace: yp[18*194*648] | gpart[4*BHW] | win0[BHW] | win1[BHW] | mats
  float* yp = (float*)d_ws;
  float* gpart = yp + (size_t)kYPF;
  int* win0 = (int*)(gpart + (size_t)4 * kBHW);
  int* win1 = win0 + (size_t)kBHW;
  float* M0 = (float*)(win1 + (size_t)kBHW);
  float* A1 = M0 + 9 * 35;
  float* sb = A1 + 9 * kCL;
  float* wsum = sb + 9;

  const int ninit = kYP4 + kWin4;
  kinit<<<(ninit + 255) / 256, 256, 0, stream>>>((float4*)yp, (int4*)win0);
  kscatter_precomp<<<470, 256, 0, stream>>>(coor0, coor1, win0, win1, W0, b0,
                                            W2, b2, Wsp, M0, A1, sb, wsum);
  kgate<<<kB * kHW4 * 4 / 256, 256, 0, stream>>>(x_rgb, W3, gpart);
  kgy<<<kBHW / 256, 256, 0, stream>>>(gpart, win0, win1, feat0, vox0, feat1,
                                      vox1, M0, A1, sb, wsum, b3, yp);
  kpass2<<<kB * kHW4 * 4 / 256, 256, 0, stream>>>(x_rgb, yp, bsp, out);
}

// Round 8
// 74.036 us; speedup vs baseline: 1.3237x; 1.1529x over previous
//
#include <hip/hip_runtime.h>

namespace {
constexpr int kH = 192, kW = 640, kHW = kH * kW;
constexpr int kW4g = kW / 4;            // 160 granules per row
constexpr int kHW4 = kHW / 4;           // 30720 granules per plane
constexpr int kB = 2, kC = 64;          // batch, image channels
constexpr int kN0 = 40000, kC0 = 32;    // level0 points/channels
constexpr int kN1 = 20000, kC1 = 64;    // level1 points/channels
constexpr int kCL = 67;                 // C1 + 3
constexpr int kBHW = kB * kHW;
// zero-padded y planes: 18 = 9 taps x B, rows H+2, pitch W+8 (interior at +1,+4)
constexpr int kPH = kH + 2, kPW = kW + 8;  // 194 x 648
constexpr int kPW4 = kPW / 4;              // 162
constexpr int kPlane = kPH * kPW;          // 125712
constexpr int kYPF = 18 * kPlane;
constexpr int kWin4 = 2 * kBHW / 4;
// border float4s per plane: row0 (162) + row193 (162) + 192 rows x {col0,col161}
constexpr int kBord = 162 + 162 + 192 * 2;  // 708
constexpr int kBordTot = 18 * kBord;        // 12744

typedef float vf4 __attribute__((ext_vector_type(4)));

// ---------------------------------------------------------------------------
// init: zero ONLY the padded-y borders (interior is fully rewritten by kgy
// each replay) and fill the two winner maps with -1.
// ---------------------------------------------------------------------------
__global__ __launch_bounds__(256) void kinit(float* __restrict__ yp,
                                             int4* __restrict__ win4) {
  int i = blockIdx.x * 256 + threadIdx.x;
  if (i < kBordTot) {
    int plane = i / kBord, r = i - plane * kBord;
    float4* base = (float4*)(yp + (size_t)plane * kPlane);
    int f4;
    if (r < 162) {
      f4 = r;                                  // row 0
    } else if (r < 324) {
      f4 = 193 * kPW4 + (r - 162);             // row 193
    } else {
      int rr = r - 324;
      int row = 1 + (rr >> 1);
      f4 = row * kPW4 + ((rr & 1) ? (kPW4 - 1) : 0);  // cols 0-3 / 644-647
    }
    base[f4] = make_float4(0.f, 0.f, 0.f, 0.f);
  } else {
    int j = i - kBordTot;
    if (j < kWin4) win4[j] = make_int4(-1, -1, -1, -1);
  }
}

// ---------------------------------------------------------------------------
// blocks 0..468: winner-index scatter (last-write-wins == max index wins)
// block 469: LDS-staged fold of all linear stages:
//   b' = W2@b0+b2; A1 = Wsp^T@W2 [9,67]; M0 = A1@W0 [9,35];
//   sb_k = Wsp[:,k].b'; wsum_k = sum_c Wsp[c,k]
// ---------------------------------------------------------------------------
__global__ __launch_bounds__(256) void kscatter_precomp(
    const float* __restrict__ coor0, const float* __restrict__ coor1,
    int* __restrict__ win0, int* __restrict__ win1,
    const float* __restrict__ W0, const float* __restrict__ b0,
    const float* __restrict__ W2, const float* __restrict__ b2,
    const float* __restrict__ Wsp, float* __restrict__ M0,
    float* __restrict__ A1g, float* __restrict__ sb,
    float* __restrict__ wsum) {
  __shared__ float W2s[kCL * kCL];
  __shared__ float W0s[kCL * 35];
  __shared__ float Wsps[kCL * 9];
  __shared__ float A1s[9 * kCL];
  __shared__ float bps[kCL];
  if (blockIdx.x < 469) {  // ---- scatter ----
    int idx = blockIdx.x * 256 + threadIdx.x;
    const float* coor;
    int* win;
    int N;
    if (idx < kB * kN0) {
      coor = coor0; win = win0; N = kN0;
    } else {
      idx -= kB * kN0;
      if (idx >= kB * kN1) return;
      coor = coor1; win = win1; N = kN1;
    }
    int b = idx / N;
    float u = coor[(size_t)idx * 2 + 0];
    float v = coor[(size_t)idx * 2 + 1];
    u = fminf(fmaxf(u, 0.f), 1.f);
    v = fminf(fmaxf(v, 0.f), 1.f);
    int r = (int)(v * (float)kH);  // row from coor[:,1]
    int c = (int)(u * (float)kW);  // col from coor[:,0]
    if (r < kH && c < kW) {
      int n = idx - b * N;
      atomicMax(&win[b * kHW + r * kW + c], n);
    }
    return;
  }
  // ---- precomp (single block, LDS-staged) ----
  const int t = threadIdx.x;
  for (int i = t; i < kCL * kCL; i += 256) W2s[i] = W2[i];
  for (int i = t; i < kCL * 35; i += 256) W0s[i] = W0[i];
  for (int i = t; i < kCL * 9; i += 256) Wsps[i] = Wsp[i];
  __syncthreads();
  if (t < kCL) {
    float s = b2[t];
    for (int j = 0; j < kCL; ++j) s += W2s[t * kCL + j] * b0[j];
    bps[t] = s;
  }
  for (int idx = t; idx < 9 * kCL; idx += 256) {
    int k = idx / kCL, j = idx - k * kCL;
    float s = 0.f;
    for (int c = 0; c < kCL; ++c) s += Wsps[c * 9 + k] * W2s[c * kCL + j];
    A1s[idx] = s;
    A1g[idx] = s;
  }
  __syncthreads();
  for (int idx = t; idx < 9 * 35; idx += 256) {
    int k = idx / 35, i = idx - k * 35;
    float s = 0.f;
    for (int j = 0; j < kCL; ++j) s += A1s[k * kCL + j] * W0s[j * 35 + i];
    M0[idx] = s;
  }
  if (t < 9) {
    float s = 0.f;
    for (int c = 0; c < kCL; ++c) s += Wsps[c * 9 + t] * bps[c];
    sb[t] = s;
  } else if (t >= 16 && t < 25) {
    int k = t - 16;
    float s = 0.f;
    for (int c = 0; c < kCL; ++c) s += Wsps[c * 9 + k];
    wsum[k] = s;
  }
}

// ---------------------------------------------------------------------------
// gate partials: 4 channel-chunks x (B*HW/4) granules, 960 blocks.
//   gpart[q][pix] = sum_{c in chunk q} W3[c] * x_rgb[b,c,pix]
// ---------------------------------------------------------------------------
__global__ __launch_bounds__(256) void kgate(const float* __restrict__ x_rgb,
                                             const float* __restrict__ W3,
                                             float* __restrict__ gpart) {
  const int j = blockIdx.x * 256 + threadIdx.x;
  const int T = kB * kHW4;             // 61440 granules
  const int q = j / T;                 // channel chunk 0..3 (uniform/block)
  const int gran = j - q * T;
  const int b = gran / kHW4;
  const int p4 = gran - b * kHW4;
  const float4* xr = (const float4*)(x_rgb + (size_t)b * kC * kHW) + p4;
  float4 acc = make_float4(0.f, 0.f, 0.f, 0.f);
#pragma unroll
  for (int cc = 0; cc < 16; ++cc) {
    const int c = q * 16 + cc;
    float wv = W3[c];
    float4 x4 = xr[(size_t)c * kHW4];
    acc.x += wv * x4.x;
    acc.y += wv * x4.y;
    acc.z += wv * x4.z;
    acc.w += wv * x4.w;
  }
  ((float4*)gpart)[j] = acc;
}

// ---------------------------------------------------------------------------
// per-SOURCE-pixel tap projection, 3-way tap-split for occupancy:
// block handles 256 pixels x 3 taps (tg = stencil row). Gathers repeat 3x
// (L2/L3-served; adjacent blocks share the pixel range for locality).
//   y[kk] = wsum[3tg+kk]*g + sb[3tg+kk] + [w0>=0] M0[3tg+kk].p0
//         + [w1>=0] A1[3tg+kk].p1
// ---------------------------------------------------------------------------
__global__ __launch_bounds__(256) void kgy(
    const float* __restrict__ gpart, const int* __restrict__ win0,
    const int* __restrict__ win1, const float* __restrict__ feat0,
    const float* __restrict__ vox0, const float* __restrict__ feat1,
    const float* __restrict__ vox1, const float* __restrict__ M0,
    const float* __restrict__ A1, const float* __restrict__ sb,
    const float* __restrict__ wsum, const float* __restrict__ b3,
    float* __restrict__ yp) {
  const int blk = blockIdx.x;
  const int tg = blk % 3;              // tap row group: taps 3tg..3tg+2
  const int pix = (blk / 3) * 256 + threadIdx.x;
  const int b = pix / kHW;
  const int pp = pix - b * kHW;
  const int h = pp / kW;
  const int w = pp - h * kW;
  const float gv = b3[0] + gpart[pix] + gpart[kBHW + pix] +
                   gpart[2 * kBHW + pix] + gpart[3 * kBHW + pix];
  float y[3];
#pragma unroll
  for (int kk = 0; kk < 3; ++kk) y[kk] = wsum[3 * tg + kk] * gv + sb[3 * tg + kk];

  const int w0 = win0[pix];
  if (w0 >= 0) {
    const float4* f0 = (const float4*)(feat0 + ((size_t)b * kN0 + w0) * kC0);
#pragma unroll
    for (int i4 = 0; i4 < 8; ++i4) {
      float4 v = f0[i4];
#pragma unroll
      for (int kk = 0; kk < 3; ++kk) {
        const float* m = M0 + (3 * tg + kk) * 35 + i4 * 4;
        y[kk] += m[0] * v.x + m[1] * v.y + m[2] * v.z + m[3] * v.w;
      }
    }
    const float* v0 = vox0 + ((size_t)b * kN0 + w0) * 3;
#pragma unroll
    for (int i = 0; i < 3; ++i) {
      float v = v0[i];
#pragma unroll
      for (int kk = 0; kk < 3; ++kk)
        y[kk] += M0[(3 * tg + kk) * 35 + kC0 + i] * v;
    }
  }
  const int w1 = win1[pix];
  if (w1 >= 0) {
    const float4* f1 = (const float4*)(feat1 + ((size_t)b * kN1 + w1) * kC1);
#pragma unroll
    for (int i4 = 0; i4 < 16; ++i4) {
      float4 v = f1[i4];
#pragma unroll
      for (int kk = 0; kk < 3; ++kk) {
        const float* m = A1 + (3 * tg + kk) * kCL + i4 * 4;
        y[kk] += m[0] * v.x + m[1] * v.y + m[2] * v.z + m[3] * v.w;
      }
    }
    const float* v1 = vox1 + ((size_t)b * kN1 + w1) * 3;
#pragma unroll
    for (int i = 0; i < 3; ++i) {
      float v = v1[i];
#pragma unroll
      for (int kk = 0; kk < 3; ++kk)
        y[kk] += A1[(3 * tg + kk) * kCL + kC1 + i] * v;
    }
  }
#pragma unroll
  for (int kk = 0; kk < 3; ++kk) {
    yp[((size_t)((3 * tg + kk) * kB + b) * kPH + (h + 1)) * kPW + 4 + w] =
        y[kk];
  }
}

// ---------------------------------------------------------------------------
// fused stencil+sigmoid+multiply: 4 px x 16 ch per thread, 960 blocks.
//   logit[p] = bsp + sum_k yp[k][p + off_k]  (padding zeros == skipped taps)
//   out[c,p] = x_rgb[c,p] * sigmoid(logit[p])   (nontemporal stores)
// ---------------------------------------------------------------------------
__global__ __launch_bounds__(256) void kpass2(const float* __restrict__ x_rgb,
                                              const float* __restrict__ yp,
                                              const float* __restrict__ bsp,
                                              float* __restrict__ out) {
  const int j = blockIdx.x * 256 + threadIdx.x;
  const int T = kB * kHW4;             // 61440 granules
  const int q = j / T;                 // channel chunk 0..3 (uniform/block)
  const int gran = j - q * T;
  const int b = gran / kHW4;
  const int p4 = gran - b * kHW4;
  const int h = p4 / kW4g;
  const int w4 = p4 - h * kW4g;

  const float bias = bsp[0];
  float4 lg = make_float4(bias, bias, bias, bias);
#pragma unroll
  for (int r = 0; r < 3; ++r) {
    const size_t rowoff = ((size_t)h + r) * kPW + 4 * w4;
    const float* pA = yp + (size_t)((3 * r + 0) * kB + b) * kPlane + rowoff;
    const float* pB = yp + (size_t)((3 * r + 1) * kB + b) * kPlane + rowoff;
    const float* pC = yp + (size_t)((3 * r + 2) * kB + b) * kPlane + rowoff;
    float LA = pA[3];
    float4 a4 = *(const float4*)(pA + 4);
    float4 b4 = *(const float4*)(pB + 4);
    float4 c4 = *(const float4*)(pC + 4);
    float RC = pC[8];
    lg.x += LA + b4.x + c4.y;
    lg.y += a4.x + b4.y + c4.z;
    lg.z += a4.y + b4.z + c4.w;
    lg.w += a4.z + b4.w + RC;
  }
  float4 att;
  att.x = 1.f / (1.f + __expf(-lg.x));
  att.y = 1.f / (1.f + __expf(-lg.y));
  att.z = 1.f / (1.f + __expf(-lg.z));
  att.w = 1.f / (1.f + __expf(-lg.w));

  const float4* xr = (const float4*)(x_rgb + (size_t)b * kC * kHW) + p4;
  vf4* op = (vf4*)(out + (size_t)b * kC * kHW) + p4;
#pragma unroll
  for (int cc = 0; cc < 16; ++cc) {
    const int c = q * 16 + cc;
    float4 x4 = xr[(size_t)c * kHW4];
    vf4 r4;
    r4.x = x4.x * att.x;
    r4.y = x4.y * att.y;
    r4.z = x4.z * att.z;
    r4.w = x4.w * att.w;
    __builtin_nontemporal_store(r4, op + (size_t)c * kHW4);
  }
}

}  // namespace

extern "C" void kernel_launch(void* const* d_in, const int* in_sizes, int n_in,
                              void* d_out, int out_size, void* d_ws,
                              size_t ws_size, hipStream_t stream) {
  const float* x_rgb = (const float*)d_in[0];
  const float* feat0 = (const float*)d_in[1];
  const float* coor0 = (const float*)d_in[2];
  const float* vox0 = (const float*)d_in[3];
  const float* feat1 = (const float*)d_in[4];
  const float* coor1 = (const float*)d_in[5];
  const float* vox1 = (const float*)d_in[6];
  const float* W0 = (const float*)d_in[7];
  const float* b0 = (const float*)d_in[8];
  const float* W2 = (const float*)d_in[9];
  const float* b2 = (const float*)d_in[10];
  const float* W3 = (const float*)d_in[11];
  const float* b3 = (const float*)d_in[12];
  const float* Wsp = (const float*)d_in[13];
  const float* bsp = (const float*)d_in[14];
  float* out = (float*)d_out;

  // workspace: yp[18*194*648] | gpart[4*BHW] | win0[BHW] | win1[BHW] | mats
  float* yp = (float*)d_ws;
  float* gpart = yp + (size_t)kYPF;
  int* win0 = (int*)(gpart + (size_t)4 * kBHW);
  int* win1 = win0 + (size_t)kBHW;
  float* M0 = (float*)(win1 + (size_t)kBHW);
  float* A1 = M0 + 9 * 35;
  float* sb = A1 + 9 * kCL;
  float* wsum = sb + 9;

  const int ninit = kBordTot + kWin4;
  kinit<<<(ninit + 255) / 256, 256, 0, stream>>>(yp, (int4*)win0);
  kscatter_precomp<<<470, 256, 0, stream>>>(coor0, coor1, win0, win1, W0, b0,
                                            W2, b2, Wsp, M0, A1, sb, wsum);
  kgate<<<kB * kHW4 * 4 / 256, 256, 0, stream>>>(x_rgb, W3, gpart);
  kgy<<<3 * kBHW / 256, 256, 0, stream>>>(gpart, win0, win1, feat0, vox0,
                                          feat1, vox1, M0, A1, sb, wsum, b3,
                                          yp);
  kpass2<<<kB * kHW4 * 4 / 256, 256, 0, stream>>>(x_rgb, yp, bsp, out);
}

// Round 9
// 70.949 us; speedup vs baseline: 1.3813x; 1.0435x over previous
//
#include <hip/hip_runtime.h>

namespace {
constexpr int kH = 192, kW = 640, kHW = kH * kW;
constexpr int kW4g = kW / 4;            // 160 granules per row
constexpr int kHW4 = kHW / 4;           // 30720 granules per plane
constexpr int kB = 2, kC = 64;          // batch, image channels
constexpr int kN0 = 40000, kC0 = 32;    // level0 points/channels
constexpr int kN1 = 20000, kC1 = 64;    // level1 points/channels
constexpr int kCL = 67;                 // C1 + 3
constexpr int kBHW = kB * kHW;
// zero-padded y planes: 18 = 9 taps x B, rows H+2, pitch W+8 (interior at +1,+4)
constexpr int kPH = kH + 2, kPW = kW + 8;  // 194 x 648
constexpr int kPW4 = kPW / 4;              // 162
constexpr int kPlane = kPH * kPW;          // 125712
constexpr int kYPF = 18 * kPlane;
constexpr int kWin4 = 2 * kBHW / 4;
// border float4s per plane: row0 (162) + row193 (162) + 192 rows x {col0,col161}
constexpr int kBord = 162 + 162 + 192 * 2;  // 708
constexpr int kBordTot = 18 * kBord;        // 12744
// K2 block partition
constexpr int kScatB = 469;   // ceil(120000/256) scatter blocks
constexpr int kGateB0 = 470;  // gate blocks start (469 = precomp)
constexpr int kGateB = kB * kHW4 * 4 / 256;  // 960

typedef float vf4 __attribute__((ext_vector_type(4)));

// ---------------------------------------------------------------------------
// init: zero ONLY the padded-y borders (interior is fully rewritten by kgy
// each replay) and fill the two winner maps with -1.
// ---------------------------------------------------------------------------
__global__ __launch_bounds__(256) void kinit(float* __restrict__ yp,
                                             int4* __restrict__ win4) {
  int i = blockIdx.x * 256 + threadIdx.x;
  if (i < kBordTot) {
    int plane = i / kBord, r = i - plane * kBord;
    float4* base = (float4*)(yp + (size_t)plane * kPlane);
    int f4;
    if (r < 162) {
      f4 = r;                                  // row 0
    } else if (r < 324) {
      f4 = 193 * kPW4 + (r - 162);             // row 193
    } else {
      int rr = r - 324;
      int row = 1 + (rr >> 1);
      f4 = row * kPW4 + ((rr & 1) ? (kPW4 - 1) : 0);  // cols 0-3 / 644-647
    }
    base[f4] = make_float4(0.f, 0.f, 0.f, 0.f);
  } else {
    int j = i - kBordTot;
    if (j < kWin4) win4[j] = make_int4(-1, -1, -1, -1);
  }
}

// ---------------------------------------------------------------------------
// K2 (heterogeneous, all parts independent given win init):
//   blocks [0,469): winner-index scatter (last-write-wins == max index wins)
//   block  469    : LDS-staged fold of linear stages ->
//        b' = W2@b0+b2; A1 = Wsp^T@W2 [9,67]; M0 = A1@W0 [9,35];
//        sb_k = Wsp[:,k].b'; wsum_k = sum_c Wsp[c,k]
//   blocks [470,1430): gate partials
//        gpart[q][pix] = sum_{c in 16-chunk q} W3[c]*x_rgb[b,c,pix]
// scatter+precomp hide under the gate's 63 MB stream.
// ---------------------------------------------------------------------------
__global__ __launch_bounds__(256) void k2(
    const float* __restrict__ coor0, const float* __restrict__ coor1,
    int* __restrict__ win0, int* __restrict__ win1,
    const float* __restrict__ W0, const float* __restrict__ b0,
    const float* __restrict__ W2, const float* __restrict__ b2,
    const float* __restrict__ Wsp, float* __restrict__ M0,
    float* __restrict__ A1g, float* __restrict__ sb, float* __restrict__ wsum,
    const float* __restrict__ x_rgb, const float* __restrict__ W3,
    float* __restrict__ gpart) {
  __shared__ float W2s[kCL * kCL];
  __shared__ float W0s[kCL * 35];
  __shared__ float Wsps[kCL * 9];
  __shared__ float A1s[9 * kCL];
  __shared__ float bps[kCL];
  const int bid = blockIdx.x;
  if (bid >= kGateB0) {  // ---- gate ----
    const int j = (bid - kGateB0) * 256 + threadIdx.x;
    const int T = kB * kHW4;           // 61440 granules
    const int q = j / T;               // channel chunk 0..3 (uniform/block)
    const int gran = j - q * T;
    const int b = gran / kHW4;
    const int p4 = gran - b * kHW4;
    const float4* xr = (const float4*)(x_rgb + (size_t)b * kC * kHW) + p4;
    float4 acc = make_float4(0.f, 0.f, 0.f, 0.f);
#pragma unroll
    for (int cc = 0; cc < 16; ++cc) {
      const int c = q * 16 + cc;
      float wv = W3[c];
      float4 x4 = xr[(size_t)c * kHW4];
      acc.x += wv * x4.x;
      acc.y += wv * x4.y;
      acc.z += wv * x4.z;
      acc.w += wv * x4.w;
    }
    ((float4*)gpart)[j] = acc;
    return;
  }
  if (bid < kScatB) {  // ---- scatter ----
    int idx = bid * 256 + threadIdx.x;
    const float* coor;
    int* win;
    int N;
    if (idx < kB * kN0) {
      coor = coor0; win = win0; N = kN0;
    } else {
      idx -= kB * kN0;
      if (idx >= kB * kN1) return;
      coor = coor1; win = win1; N = kN1;
    }
    int b = idx / N;
    float u = coor[(size_t)idx * 2 + 0];
    float v = coor[(size_t)idx * 2 + 1];
    u = fminf(fmaxf(u, 0.f), 1.f);
    v = fminf(fmaxf(v, 0.f), 1.f);
    int r = (int)(v * (float)kH);  // row from coor[:,1]
    int c = (int)(u * (float)kW);  // col from coor[:,0]
    if (r < kH && c < kW) {
      int n = idx - b * N;
      atomicMax(&win[b * kHW + r * kW + c], n);
    }
    return;
  }
  // ---- precomp (block 469, LDS-staged) ----
  const int t = threadIdx.x;
  for (int i = t; i < kCL * kCL; i += 256) W2s[i] = W2[i];
  for (int i = t; i < kCL * 35; i += 256) W0s[i] = W0[i];
  for (int i = t; i < kCL * 9; i += 256) Wsps[i] = Wsp[i];
  __syncthreads();
  if (t < kCL) {
    float s = b2[t];
    for (int j = 0; j < kCL; ++j) s += W2s[t * kCL + j] * b0[j];
    bps[t] = s;
  }
  for (int idx = t; idx < 9 * kCL; idx += 256) {
    int k = idx / kCL, j = idx - k * kCL;
    float s = 0.f;
    for (int c = 0; c < kCL; ++c) s += Wsps[c * 9 + k] * W2s[c * kCL + j];
    A1s[idx] = s;
    A1g[idx] = s;
  }
  __syncthreads();
  for (int idx = t; idx < 9 * 35; idx += 256) {
    int k = idx / 35, i = idx - k * 35;
    float s = 0.f;
    for (int j = 0; j < kCL; ++j) s += A1s[k * kCL + j] * W0s[j * 35 + i];
    M0[idx] = s;
  }
  if (t < 9) {
    float s = 0.f;
    for (int c = 0; c < kCL; ++c) s += Wsps[c * 9 + t] * bps[c];
    sb[t] = s;
  } else if (t >= 16 && t < 25) {
    int k = t - 16;
    float s = 0.f;
    for (int c = 0; c < kCL; ++c) s += Wsps[c * 9 + k];
    wsum[k] = s;
  }
}

// ---------------------------------------------------------------------------
// per-SOURCE-pixel tap projection, 3-way tap-split for occupancy:
// block handles 256 pixels x 3 taps (tg = stencil row). Gathers repeat 3x
// (L2/L3-served; adjacent blocks share the pixel range for locality).
//   y[kk] = wsum[3tg+kk]*g + sb[3tg+kk] + [w0>=0] M0[3tg+kk].p0
//         + [w1>=0] A1[3tg+kk].p1
// ---------------------------------------------------------------------------
__global__ __launch_bounds__(256) void kgy(
    const float* __restrict__ gpart, const int* __restrict__ win0,
    const int* __restrict__ win1, const float* __restrict__ feat0,
    const float* __restrict__ vox0, const float* __restrict__ feat1,
    const float* __restrict__ vox1, const float* __restrict__ M0,
    const float* __restrict__ A1, const float* __restrict__ sb,
    const float* __restrict__ wsum, const float* __restrict__ b3,
    float* __restrict__ yp) {
  const int blk = blockIdx.x;
  const int tg = blk % 3;              // tap row group: taps 3tg..3tg+2
  const int pix = (blk / 3) * 256 + threadIdx.x;
  const int b = pix / kHW;
  const int pp = pix - b * kHW;
  const int h = pp / kW;
  const int w = pp - h * kW;
  const float gv = b3[0] + gpart[pix] + gpart[kBHW + pix] +
                   gpart[2 * kBHW + pix] + gpart[3 * kBHW + pix];
  float y[3];
#pragma unroll
  for (int kk = 0; kk < 3; ++kk)
    y[kk] = wsum[3 * tg + kk] * gv + sb[3 * tg + kk];

  const int w0 = win0[pix];
  if (w0 >= 0) {
    const float4* f0 = (const float4*)(feat0 + ((size_t)b * kN0 + w0) * kC0);
#pragma unroll
    for (int i4 = 0; i4 < 8; ++i4) {
      float4 v = f0[i4];
#pragma unroll
      for (int kk = 0; kk < 3; ++kk) {
        const float* m = M0 + (3 * tg + kk) * 35 + i4 * 4;
        y[kk] += m[0] * v.x + m[1] * v.y + m[2] * v.z + m[3] * v.w;
      }
    }
    const float* v0 = vox0 + ((size_t)b * kN0 + w0) * 3;
#pragma unroll
    for (int i = 0; i < 3; ++i) {
      float v = v0[i];
#pragma unroll
      for (int kk = 0; kk < 3; ++kk)
        y[kk] += M0[(3 * tg + kk) * 35 + kC0 + i] * v;
    }
  }
  const int w1 = win1[pix];
  if (w1 >= 0) {
    const float4* f1 = (const float4*)(feat1 + ((size_t)b * kN1 + w1) * kC1);
#pragma unroll
    for (int i4 = 0; i4 < 16; ++i4) {
      float4 v = f1[i4];
#pragma unroll
      for (int kk = 0; kk < 3; ++kk) {
        const float* m = A1 + (3 * tg + kk) * kCL + i4 * 4;
        y[kk] += m[0] * v.x + m[1] * v.y + m[2] * v.z + m[3] * v.w;
      }
    }
    const float* v1 = vox1 + ((size_t)b * kN1 + w1) * 3;
#pragma unroll
    for (int i = 0; i < 3; ++i) {
      float v = v1[i];
#pragma unroll
      for (int kk = 0; kk < 3; ++kk)
        y[kk] += A1[(3 * tg + kk) * kCL + kC1 + i] * v;
    }
  }
#pragma unroll
  for (int kk = 0; kk < 3; ++kk) {
    yp[((size_t)((3 * tg + kk) * kB + b) * kPH + (h + 1)) * kPW + 4 + w] =
        y[kk];
  }
}

// ---------------------------------------------------------------------------
// fused stencil+sigmoid+multiply: 4 px x 16 ch per thread, 960 blocks.
//   logit[p] = bsp + sum_k yp[k][p + off_k]  (padding zeros == skipped taps)
//   out[c,p] = x_rgb[c,p] * sigmoid(logit[p])
// x loads + out stores nontemporal (last reader / never re-read).
// ---------------------------------------------------------------------------
__global__ __launch_bounds__(256) void kpass2(const float* __restrict__ x_rgb,
                                              const float* __restrict__ yp,
                                              const float* __restrict__ bsp,
                                              float* __restrict__ out) {
  const int j = blockIdx.x * 256 + threadIdx.x;
  const int T = kB * kHW4;             // 61440 granules
  const int q = j / T;                 // channel chunk 0..3 (uniform/block)
  const int gran = j - q * T;
  const int b = gran / kHW4;
  const int p4 = gran - b * kHW4;
  const int h = p4 / kW4g;
  const int w4 = p4 - h * kW4g;

  const float bias = bsp[0];
  float4 lg = make_float4(bias, bias, bias, bias);
#pragma unroll
  for (int r = 0; r < 3; ++r) {
    const size_t rowoff = ((size_t)h + r) * kPW + 4 * w4;
    const float* pA = yp + (size_t)((3 * r + 0) * kB + b) * kPlane + rowoff;
    const float* pB = yp + (size_t)((3 * r + 1) * kB + b) * kPlane + rowoff;
    const float* pC = yp + (size_t)((3 * r + 2) * kB + b) * kPlane + rowoff;
    float LA = pA[3];
    float4 a4 = *(const float4*)(pA + 4);
    float4 b4 = *(const float4*)(pB + 4);
    float4 c4 = *(const float4*)(pC + 4);
    float RC = pC[8];
    lg.x += LA + b4.x + c4.y;
    lg.y += a4.x + b4.y + c4.z;
    lg.z += a4.y + b4.z + c4.w;
    lg.w += a4.z + b4.w + RC;
  }
  float4 att;
  att.x = 1.f / (1.f + __expf(-lg.x));
  att.y = 1.f / (1.f + __expf(-lg.y));
  att.z = 1.f / (1.f + __expf(-lg.z));
  att.w = 1.f / (1.f + __expf(-lg.w));

  const vf4* xr = (const vf4*)(x_rgb + (size_t)b * kC * kHW) + p4;
  vf4* op = (vf4*)(out + (size_t)b * kC * kHW) + p4;
#pragma unroll
  for (int cc = 0; cc < 16; ++cc) {
    const int c = q * 16 + cc;
    vf4 x4 = __builtin_nontemporal_load(xr + (size_t)c * kHW4);
    vf4 r4;
    r4.x = x4.x * att.x;
    r4.y = x4.y * att.y;
    r4.z = x4.z * att.z;
    r4.w = x4.w * att.w;
    __builtin_nontemporal_store(r4, op + (size_t)c * kHW4);
  }
}

}  // namespace

extern "C" void kernel_launch(void* const* d_in, const int* in_sizes, int n_in,
                              void* d_out, int out_size, void* d_ws,
                              size_t ws_size, hipStream_t stream) {
  const float* x_rgb = (const float*)d_in[0];
  const float* feat0 = (const float*)d_in[1];
  const float* coor0 = (const float*)d_in[2];
  const float* vox0 = (const float*)d_in[3];
  const float* feat1 = (const float*)d_in[4];
  const float* coor1 = (const float*)d_in[5];
  const float* vox1 = (const float*)d_in[6];
  const float* W0 = (const float*)d_in[7];
  const float* b0 = (const float*)d_in[8];
  const float* W2 = (const float*)d_in[9];
  const float* b2 = (const float*)d_in[10];
  const float* W3 = (const float*)d_in[11];
  const float* b3 = (const float*)d_in[12];
  const float* Wsp = (const float*)d_in[13];
  const float* bsp = (const float*)d_in[14];
  float* out = (float*)d_out;

  // workspace: yp[18*194*648] | gpart[4*BHW] | win0[BHW] | win1[BHW] | mats
  float* yp = (float*)d_ws;
  float* gpart = yp + (size_t)kYPF;
  int* win0 = (int*)(gpart + (size_t)4 * kBHW);
  int* win1 = win0 + (size_t)kBHW;
  float* M0 = (float*)(win1 + (size_t)kBHW);
  float* A1 = M0 + 9 * 35;
  float* sb = A1 + 9 * kCL;
  float* wsum = sb + 9;

  const int ninit = kBordTot + kWin4;
  kinit<<<(ninit + 255) / 256, 256, 0, stream>>>(yp, (int4*)win0);
  k2<<<kGateB0 + kGateB, 256, 0, stream>>>(coor0, coor1, win0, win1, W0, b0,
                                           W2, b2, Wsp, M0, A1, sb, wsum,
                                           x_rgb, W3, gpart);
  kgy<<<3 * kBHW / 256, 256, 0, stream>>>(gpart, win0, win1, feat0, vox0,
                                          feat1, vox1, M0, A1, sb, wsum, b3,
                                          yp);
  kpass2<<<kB * kHW4 * 4 / 256, 256, 0, stream>>>(x_rgb, yp, bsp, out);
}